// Round 9
// baseline (26.840 us; speedup 1.0000x reference)
//
#include <hip/hip_runtime.h>

#define B_SZ 512
#define V_SZ 1024
#define K_SZ 64
#define C_SZ 2048
#define A_SZ 128

#define LOG2E 1.4426950408889634f

__device__ __forceinline__ unsigned bf16_rne(float f) {
  unsigned u = __float_as_uint(f);
  return (u + 0x7FFFu + ((u >> 16) & 1u)) >> 16;   // round-nearest-even
}

// ---------------------------------------------------------------------------
// Kernel A (R5-validated): pack Wa/Wb/Wk (fp32 [1024][64]) into bf16 pairs:
//   wpk[m][v2*64+k] = bf16(W[2v2][k]) | bf16(W[2v2+1][k])<<16
// Halves phase-1 per-CU bytes (the measured bottleneck).
// ---------------------------------------------------------------------------
__global__ __launch_bounds__(256) void gw_convW(
    const float* __restrict__ Wa, const float* __restrict__ Wb,
    const float* __restrict__ Wk, unsigned* __restrict__ wpk) {
  const int i = blockIdx.x * 256 + threadIdx.x;   // over 3*512*64 exactly
  const int m = i / (512 * K_SZ);
  const int r = i % (512 * K_SZ);
  const int v2 = r >> 6;
  const int k = r & 63;
  const float* __restrict__ W = (m == 0) ? Wa : (m == 1) ? Wb : Wk;
  const float w0 = W[(2 * v2) * K_SZ + k];        // 256B coalesced
  const float w1 = W[(2 * v2 + 1) * K_SZ + k];
  wpk[i] = bf16_rne(w0) | (bf16_rne(w1) << 16);
}

// ---------------------------------------------------------------------------
// Fused (R8 structure): one block per 2 batch rows, 768 threads (12 waves).
// Phase 1: wave w -> matrix m=w>>2, v2-quarter q=w&3 (128 iters);
//   per iter: 1 packed-W u32 load + 1 ds_read_b128 (2 rows x 2 v's) +
//   2 unpack + 4 FMA. LDS reduce; alpha/beta/kappa stay in LDS.
// Phase 2 (verbatim R8): cutoff CL (term <= 2^-150), phi -> LDS+global,
//   exact zeros beyond, window = phi[0:CL) @ text[0:CL).
// ---------------------------------------------------------------------------
__global__ __launch_bounds__(768) void gw_fused(
    const float* __restrict__ x, const float* __restrict__ text,
    const float* __restrict__ prev_kappa, const unsigned* __restrict__ wpk,
    const float* __restrict__ ba, const float* __restrict__ bb,
    const float* __restrict__ bk,
    float* __restrict__ out_phi, float* __restrict__ out_kappa,
    float* __restrict__ out_window) {
  __shared__ float2 xs2[V_SZ];            // 8KB  {row0[v], row1[v]} per v
  __shared__ float part[12][2][K_SZ];     // 6KB  [wave][row][k]
  __shared__ float al[2][K_SZ];
  __shared__ float bn[2][K_SZ];           // -log2(e)*beta
  __shared__ float kap[2][K_SZ];
  __shared__ float bnd[2][K_SZ];
  __shared__ int cl_s[2];
  __shared__ float phi_s[2][C_SZ];        // 16KB
  __shared__ float4 red[2][12][32];       // 12KB

  const int tid = threadIdx.x;
  const int b0 = blockIdx.x * 2;

  // ---- stage x row pair ----
  {
    const float* x0 = x + (size_t)b0 * V_SZ;
    const float* x1 = x0 + V_SZ;
    for (int i = tid; i < V_SZ; i += 768)
      xs2[i] = make_float2(x0[i], x1[i]);   // coalesced sweeps
  }
  __syncthreads();

  // ---- Phase 1: GEMM on packed bf16 W ----
  {
    const int w = tid >> 6;     // wave 0..11
    const int m = w >> 2;       // 0=alpha, 1=beta, 2=kappa
    const int q = w & 3;        // v2-quarter
    const int k = tid & 63;
    const unsigned* __restrict__ Wp = wpk + m * (512 * K_SZ);

    float acc0 = 0.f, acc1 = 0.f;
    const int v20 = q * 128;
#pragma unroll 8
    for (int v2 = v20; v2 < v20 + 128; ++v2) {
      unsigned w2 = Wp[v2 * K_SZ + k];               // 256B coalesced
      float w0 = __uint_as_float(w2 << 16);          // bf16 of W[2v2]
      float w1 = __uint_as_float(w2 & 0xFFFF0000u);  // bf16 of W[2v2+1]
      float4 xv = *(const float4*)&xs2[2 * v2];      // one ds_read_b128
      acc0 = fmaf(xv.x, w0, acc0);   // row0, v=2v2
      acc1 = fmaf(xv.y, w0, acc1);   // row1, v=2v2
      acc0 = fmaf(xv.z, w1, acc0);   // row0, v=2v2+1
      acc1 = fmaf(xv.w, w1, acc1);   // row1, v=2v2+1
    }
    part[w][0][k] = acc0;
    part[w][1][k] = acc1;
  }
  __syncthreads();

  if (tid < 384) {
    const int mm = tid >> 7;         // 0=alpha, 1=beta, 2=kappa
    const int r = (tid >> 6) & 1;
    const int kk = tid & 63;
    float s = part[mm * 4 + 0][r][kk] + part[mm * 4 + 1][r][kk] +
              part[mm * 4 + 2][r][kk] + part[mm * 4 + 3][r][kk];
    const float bias = ((mm == 0) ? ba : (mm == 1) ? bb : bk)[kk];
    const float e = expf(s + bias);
    if (mm == 0) {
      al[r][kk] = e;
    } else if (mm == 1) {
      bn[r][kk] = -LOG2E * e;
    } else {
      float nk = prev_kappa[(b0 + r) * K_SZ + kk] + e;
      kap[r][kk] = nk;
      out_kappa[(b0 + r) * K_SZ + kk] = nk;
    }
  }
  __syncthreads();

  // ---- cutoff per row: term <= 2^-150 for c >= bnd ----
  if (tid < 128) {
    const int r = tid >> 6, kk = tid & 63;
    float num = 150.f + fmaxf(0.f, log2f(al[r][kk]));
    bnd[r][kk] = kap[r][kk] + sqrtf(num / (-bn[r][kk]));
  }
  __syncthreads();
  if (tid < 2) {
    float mx = 0.f;
    for (int i = 0; i < K_SZ; ++i) mx = fmaxf(mx, bnd[tid][i]);
    mx = fminf(mx, (float)C_SZ);     // sanitizes inf -> full compute
    int cl = (int)mx + 1;
    cl = (cl + 15) & ~15;
    if (cl > C_SZ) cl = C_SZ;
    cl_s[tid] = cl;
  }
  __syncthreads();

  // ---- Phase 2: halves (wave-aligned) own one row each ----
  const int half = tid / 384;        // 0 or 1
  const int t2 = tid - half * 384;   // 0..383
  const int r = half;
  const int b = b0 + r;
  const int CL = cl_s[r];

  // phi for c < CL
  for (int c = t2; c < CL; c += 384) {
    float cf = (float)c;
    float s = 0.f;
#pragma unroll
    for (int kk = 0; kk < K_SZ; ++kk) {
      float d = kap[r][kk] - cf;
      s += al[r][kk] * exp2f(bn[r][kk] * d * d);
    }
    phi_s[r][c] = s;
    out_phi[(size_t)b * C_SZ + c] = s;
  }
  // exact zeros for c >= CL
  {
    float4 z = make_float4(0.f, 0.f, 0.f, 0.f);
    float4* po = (float4*)(out_phi + (size_t)b * C_SZ);
    for (int i = (CL >> 2) + t2; i < C_SZ / 4; i += 384) po[i] = z;
  }
  __syncthreads();

  // window over [0, CL) rows of text
  {
    const float4* __restrict__ t4 =
        (const float4*)(text + (size_t)b * C_SZ * A_SZ);
    const int a4 = t2 & 31;   // float4 column (covers A=128)
    const int cr = t2 >> 5;   // 12 parallel c-rows per half

    float4 acc = make_float4(0.f, 0.f, 0.f, 0.f);
    for (int cc = cr; cc < CL; cc += 12) {
      float p = phi_s[r][cc];
      float4 t = t4[cc * 32 + a4];   // coalesced 512B per row
      acc.x = fmaf(p, t.x, acc.x);
      acc.y = fmaf(p, t.y, acc.y);
      acc.z = fmaf(p, t.z, acc.z);
      acc.w = fmaf(p, t.w, acc.w);
    }
    red[r][cr][a4] = acc;
  }
  __syncthreads();

  if (t2 < 32) {
    float4 wv = red[r][0][t2];
#pragma unroll
    for (int i = 1; i < 12; ++i) {
      float4 rr = red[r][i][t2];
      wv.x += rr.x; wv.y += rr.y; wv.z += rr.z; wv.w += rr.w;
    }
    ((float4*)(out_window + (size_t)b * A_SZ))[t2] = wv;
  }
}

extern "C" void kernel_launch(void* const* d_in, const int* in_sizes, int n_in,
                              void* d_out, int out_size, void* d_ws, size_t ws_size,
                              hipStream_t stream) {
  const float* x    = (const float*)d_in[0];
  const float* text = (const float*)d_in[1];
  const float* pk   = (const float*)d_in[2];
  const float* Wa   = (const float*)d_in[3];
  const float* ba   = (const float*)d_in[4];
  const float* Wb   = (const float*)d_in[5];
  const float* bb   = (const float*)d_in[6];
  const float* Wk   = (const float*)d_in[7];
  const float* bk   = (const float*)d_in[8];

  float* out        = (float*)d_out;
  float* out_phi    = out;                              // B*C
  float* out_kappa  = out + (size_t)B_SZ * C_SZ;        // B*K
  float* out_win    = out_kappa + (size_t)B_SZ * K_SZ;  // B*A

  unsigned* wpk     = (unsigned*)d_ws;                  // 3*512*64*4 = 393KB

  gw_convW<<<(3 * 512 * K_SZ) / 256, 256, 0, stream>>>(Wa, Wb, Wk, wpk);
  gw_fused<<<B_SZ / 2, 768, 0, stream>>>(x, text, pk, wpk, ba, bb, bk,
                                         out_phi, out_kappa, out_win);
}